// Round 4
// baseline (212.429 us; speedup 1.0000x reference)
//
#include <hip/hip_runtime.h>
#include <stdint.h>

#define Bv 4
#define Nv 2048
#define Kv 30
#define DIMv 128
#define NROW (Bv * Nv)
#define NEDGE (Bv * Nv * Kv)

// ---------------- Kernel A: O frame precompute -> ws ----------------
__global__ __launch_bounds__(256) void o_kernel(const float* __restrict__ X,
                                                float* __restrict__ O9) {
    int id = blockIdx.x * 256 + threadIdx.x;
    if (id >= NROW) return;
    int b = id >> 11;
    int n = id & (Nv - 1);
    float o[9] = {0.f, 0.f, 0.f, 0.f, 0.f, 0.f, 0.f, 0.f, 0.f};
    if (n >= 1 && n <= Nv - 3) {
        const float* Xb = X + (size_t)b * Nv * 3;
        float lx = Xb[(Nv - 1) * 3 + 0], ly = Xb[(Nv - 1) * 3 + 1], lz = Xb[(Nv - 1) * 3 + 2];
        float ax = Xb[n * 3 + 0] - lx, ay = Xb[n * 3 + 1] - ly, az = Xb[n * 3 + 2] - lz;
        float bx = Xb[(n + 1) * 3 + 0] - lx, by = Xb[(n + 1) * 3 + 1] - ly, bz = Xb[(n + 1) * 3 + 2] - lz;
        float an = fmaxf(sqrtf(ax * ax + ay * ay + az * az), 1e-12f);
        ax /= an; ay /= an; az /= an;
        float bn = fmaxf(sqrtf(bx * bx + by * by + bz * bz), 1e-12f);
        bx /= bn; by /= bn; bz /= bn;
        float cx = ay * bz - az * by, cy = az * bx - ax * bz, cz = ax * by - ay * bx;
        float cn = fmaxf(sqrtf(cx * cx + cy * cy + cz * cz), 1e-12f);
        cx /= cn; cy /= cn; cz /= cn;
        float ox = ax - bx, oy = ay - by, oz = az - bz;
        float on = fmaxf(sqrtf(ox * ox + oy * oy + oz * oz), 1e-12f);
        ox /= on; oy /= on; oz /= on;
        float tx = oy * cz - oz * cy, ty = oz * cx - ox * cz, tz = ox * cy - oy * cx;
        o[0] = ox; o[1] = cx; o[2] = tx;
        o[3] = oy; o[4] = cy; o[5] = ty;
        o[6] = oz; o[7] = cz; o[8] = tz;
    }
#pragma unroll
    for (int i = 0; i < 9; ++i) O9[(size_t)id * 9 + i] = o[i];
}

// ---------------- Kernel B: top-K per row (1 wave / row), bit-exact ----------------
// u64 keys (value_bits<<32 | j): one 6-step butterfly per round; min-key gives
// exact reference tie-breaking (lowest index among equal values).
__global__ __launch_bounds__(256) void topk_kernel(const float* __restrict__ X,
                                                   const float* __restrict__ mask,
                                                   int* __restrict__ idx_ws,
                                                   float* __restrict__ dn_ws,
                                                   float* __restrict__ idxf_out) {
    const int lane = threadIdx.x & 63;
    const int wv = threadIdx.x >> 6;
    const int row = blockIdx.x * 4 + wv;
    const int b = row >> 11;
    const int n = row & (Nv - 1);
    const float* Xb = X + (size_t)b * Nv * 3;
    const float* Mb = mask + (size_t)b * Nv;
    const float xn = Xb[n * 3 + 0], yn = Xb[n * 3 + 1], zn = Xb[n * 3 + 2];
    const float mi = Mb[n];

    // pass 1: exact D bits (nonneg -> u32 order == float order), row max
    uint32_t a[4][8];
    uint32_t bmax = 0;
#pragma unroll
    for (int gg = 0; gg < 4; ++gg)
#pragma unroll
        for (int s = 0; s < 8; ++s) {
            int j = (gg * 8 + s) * 64 + lane;
            float dx = __fsub_rn(xn, Xb[j * 3 + 0]);
            float dy = __fsub_rn(yn, Xb[j * 3 + 1]);
            float dz = __fsub_rn(zn, Xb[j * 3 + 2]);
            float ss = __fadd_rn(__fadd_rn(__fmul_rn(dx, dx), __fmul_rn(dy, dy)),
                                 __fmul_rn(dz, dz));
            float D = __fmul_rn(__fmul_rn(mi, Mb[j]), __fsqrt_rn(__fadd_rn(ss, 1e-6f)));
            uint32_t bits = __float_as_uint(D);
            a[gg][s] = bits;
            bmax = (bits > bmax) ? bits : bmax;
        }
#pragma unroll
    for (int m = 1; m < 64; m <<= 1) {
        uint32_t o = __shfl_xor(bmax, m, 64);
        bmax = (o > bmax) ? o : bmax;
    }
    const float dmax = __uint_as_float(bmax);

    // pass 2: adjust in place + per-group min-key cache
    unsigned long long gkey[4];
#pragma unroll
    for (int gg = 0; gg < 4; ++gg) {
        unsigned long long kmin = ~0ull;
#pragma unroll
        for (int s = 0; s < 8; ++s) {
            int j = (gg * 8 + s) * 64 + lane;
            float m2 = __fmul_rn(mi, Mb[j]);
            float adj = __fadd_rn(__uint_as_float(a[gg][s]),
                                  __fmul_rn(__fsub_rn(1.f, m2), dmax));
            uint32_t bits = __float_as_uint(adj);
            a[gg][s] = bits;
            unsigned long long kk = ((unsigned long long)bits << 32) | (unsigned)j;
            kmin = (kk < kmin) ? kk : kmin;
        }
        gkey[gg] = kmin;
    }

    const int rk = row * Kv;
    for (int p = 0; p < Kv; ++p) {
        unsigned long long k0 = (gkey[0] < gkey[1]) ? gkey[0] : gkey[1];
        unsigned long long k1 = (gkey[2] < gkey[3]) ? gkey[2] : gkey[3];
        unsigned long long key = (k0 < k1) ? k0 : k1;
#pragma unroll
        for (int m = 1; m < 64; m <<= 1) {
            unsigned long long o = __shfl_xor(key, m, 64);
            key = (o < key) ? o : key;
        }
        const uint32_t mj = (uint32_t)(key & 0xFFFFFFFFull);

        if (lane == 0) {
            idx_ws[rk + p] = (int)mj;
            dn_ws[rk + p] = __uint_as_float((uint32_t)(key >> 32));
            idxf_out[rk + p] = (float)mj;
        }

        // owner lane invalidates + recomputes its group's min-key
        if ((mj & 63u) == (uint32_t)lane) {
            const uint32_t ww = mj >> 6;
            const uint32_t og = ww >> 3;
            const uint32_t os = ww & 7u;
#define RESCAN(G)                                                              \
            {                                                                  \
                unsigned long long kmin = ~0ull;                               \
                _Pragma("unroll")                                              \
                for (int s = 0; s < 8; ++s) {                                  \
                    uint32_t val = ((uint32_t)s == os) ? 0xFFFFFFFFu           \
                                                       : a[G][s];              \
                    a[G][s] = val;                                             \
                    unsigned long long kk = ((unsigned long long)val << 32) |  \
                        (unsigned)((((G) * 8 + s) << 6) | lane);               \
                    kmin = (kk < kmin) ? kk : kmin;                            \
                }                                                              \
                gkey[G] = kmin;                                                \
            }
            if (og == 0) RESCAN(0)
            else if (og == 1) RESCAN(1)
            else if (og == 2) RESCAN(2)
            else RESCAN(3)
#undef RESCAN
        }
    }
}

// ---------------- Kernel C: block per (b,n): features + GEMM + in-reg LN ----------------
__device__ __forceinline__ float sgnf(float x) {
    return (x > 0.f) ? 1.f : ((x < 0.f) ? -1.f : 0.f);
}

__global__ __launch_bounds__(256) void edge_kernel(const float* __restrict__ X,
                                                   const float* __restrict__ W,
                                                   const float* __restrict__ be,
                                                   const float* __restrict__ gain,
                                                   const float* __restrict__ bias,
                                                   const float* __restrict__ O9,
                                                   const int* __restrict__ idx_ws,
                                                   const float* __restrict__ dn_ws,
                                                   float* __restrict__ E) {
    __shared__ float fls[Kv][40];   // 39 features (+[39]=0 pad)
    __shared__ float sO[9];
    __shared__ float sX[3];
    __shared__ int   sidx[Kv];
    __shared__ float sdn[Kv];

    const int t = threadIdx.x;
    const int lane = t & 63;
    const int w = t >> 6;
    const int row = blockIdx.x;
    const int b = row >> 11;
    const int n = row & (Nv - 1);
    const int bN = b * Nv;
    const size_t ebase = (size_t)row * Kv;

    // ---- stage per-row data ----
    if (t < Kv) {
        sidx[t] = idx_ws[ebase + t];
        sdn[t] = dn_ws[ebase + t];
    } else if (t >= 32 && t < 41) {
        sO[t - 32] = O9[(size_t)row * 9 + (t - 32)];
    } else if (t >= 48 && t < 51) {
        sX[t - 48] = X[(size_t)row * 3 + (t - 48)];
    }
    __syncthreads();

    // ---- features ----
    if (t < 240) {
        const int e = t >> 3;
        const int p = t & 7;
        const float c = -0.5756462732485115f;  // -ln(10000)/16
        float freq = expf((float)(2 * p) * c);
        float ang = ((float)sidx[e] - (float)n) * freq;
        fls[e][p] = cosf(ang);
        fls[e][p + 8] = sinf(ang);
        float dn = sdn[e];
        float mu0 = (float)p * (20.0f / 15.0f);
        float z0 = (dn - mu0) * 0.8f;
        fls[e][16 + p] = expf(-z0 * z0);
        float mu1 = (float)(p + 8) * (20.0f / 15.0f);
        float z1 = (dn - mu1) * 0.8f;
        fls[e][24 + p] = expf(-z1 * z1);
    }
    if (t < Kv) {
        const int e = t;
        const int j = sidx[e];
        float oi[9], oj[9];
#pragma unroll
        for (int i = 0; i < 9; ++i) {
            oi[i] = sO[i];
            oj[i] = O9[((size_t)bN + j) * 9 + i];
        }
        float dx = X[((size_t)bN + j) * 3 + 0] - sX[0];
        float dy = X[((size_t)bN + j) * 3 + 1] - sX[1];
        float dz = X[((size_t)bN + j) * 3 + 2] - sX[2];
        float u0 = oi[0] * dx + oi[1] * dy + oi[2] * dz;
        float u1 = oi[3] * dx + oi[4] * dy + oi[5] * dz;
        float u2 = oi[6] * dx + oi[7] * dy + oi[8] * dz;
        float un = fmaxf(sqrtf(u0 * u0 + u1 * u1 + u2 * u2), 1e-12f);
        fls[e][32] = u0 / un;
        fls[e][33] = u1 / un;
        fls[e][34] = u2 / un;
        float R00 = oi[0] * oj[0] + oi[3] * oj[3] + oi[6] * oj[6];
        float R11 = oi[1] * oj[1] + oi[4] * oj[4] + oi[7] * oj[7];
        float R22 = oi[2] * oj[2] + oi[5] * oj[5] + oi[8] * oj[8];
        float R21 = oi[2] * oj[1] + oi[5] * oj[4] + oi[8] * oj[7];
        float R12 = oi[1] * oj[2] + oi[4] * oj[5] + oi[7] * oj[8];
        float R02 = oi[0] * oj[2] + oi[3] * oj[5] + oi[6] * oj[8];
        float R20 = oi[2] * oj[0] + oi[5] * oj[3] + oi[8] * oj[6];
        float R10 = oi[1] * oj[0] + oi[4] * oj[3] + oi[7] * oj[6];
        float R01 = oi[0] * oj[1] + oi[3] * oj[4] + oi[6] * oj[7];
        float m0 = 0.5f * sqrtf(fabsf(1.0f + (R00 - R11 - R22)));
        float m1 = 0.5f * sqrtf(fabsf(1.0f + (-R00 + R11 - R22)));
        float m2 = 0.5f * sqrtf(fabsf(1.0f + (-R00 - R11 + R22)));
        float s0 = sgnf(R21 - R12);
        float s1 = sgnf(R02 - R20);
        float s2 = sgnf(R10 - R01);
        float tr = 1.0f + R00 + R11 + R22;
        float w4 = sqrtf(fmaxf(tr, 0.f)) * 0.5f;
        float q0 = s0 * m0, q1 = s1 * m1, q2 = s2 * m2;
        float qn = fmaxf(sqrtf(q0 * q0 + q1 * q1 + q2 * q2 + w4 * w4), 1e-12f);
        fls[e][35] = q0 / qn;
        fls[e][36] = q1 / qn;
        fls[e][37] = q2 / qn;
        fls[e][38] = w4 / qn;
        fls[e][39] = 0.f;   // pad so the 10th float4 is finite
    }
    __syncthreads();

    // ---- GEMM: 2 channels/thread (lane, lane+64); wave w owns {8,8,7,7} edges ----
    const int c0 = lane, c1 = lane + 64;
    float w0[40], w1[40];
#pragma unroll
    for (int i = 0; i < 39; ++i) {
        w0[i] = W[i * DIMv + c0];
        w1[i] = W[i * DIMv + c1];
    }
    w0[39] = 0.f; w1[39] = 0.f;
    const float be0 = be[c0], be1 = be[c1];
    const float g0 = gain[c0], g1 = gain[c1];
    const float bb0 = bias[c0], bb1 = bias[c1];
    const int off = (w < 2) ? w * 8 : 16 + (w - 2) * 7;
    const int cnt = (w < 2) ? 8 : 7;

    float a0[8], a1[8];
#pragma unroll
    for (int k = 0; k < 8; ++k) {
        if (k < cnt) {
            const float* fr = &fls[off + k][0];
            float s0 = be0, s1 = be1;
#pragma unroll
            for (int q = 0; q < 10; ++q) {
                float4 v = *(const float4*)(fr + 4 * q);
                s0 = fmaf(v.x, w0[4 * q + 0], s0); s1 = fmaf(v.x, w1[4 * q + 0], s1);
                s0 = fmaf(v.y, w0[4 * q + 1], s0); s1 = fmaf(v.y, w1[4 * q + 1], s1);
                s0 = fmaf(v.z, w0[4 * q + 2], s0); s1 = fmaf(v.z, w1[4 * q + 2], s1);
                s0 = fmaf(v.w, w0[4 * q + 3], s0); s1 = fmaf(v.w, w1[4 * q + 3], s1);
            }
            a0[k] = s0; a1[k] = s1;
        }
    }

    // ---- LayerNorm in registers (channels of an edge live in one wave) ----
#pragma unroll
    for (int k = 0; k < 8; ++k) {
        if (k < cnt) {
            float s = a0[k] + a1[k];
#pragma unroll
            for (int m = 1; m < 64; m <<= 1) s += __shfl_xor(s, m, 64);
            float mu = s * (1.0f / 128.0f);
            float d0 = a0[k] - mu, d1 = a1[k] - mu;
            float vv = d0 * d0 + d1 * d1;
#pragma unroll
            for (int m = 1; m < 64; m <<= 1) vv += __shfl_xor(vv, m, 64);
            float inv = 1.0f / (sqrtf(vv * (1.0f / 127.0f)) + 1e-6f);
            float* out = E + (ebase + off + k) * DIMv;
            out[c0] = g0 * d0 * inv + bb0;
            out[c1] = g1 * d1 * inv + bb1;
        }
    }
}

// ---------------- launcher ----------------
extern "C" void kernel_launch(void* const* d_in, const int* in_sizes, int n_in,
                              void* d_out, int out_size, void* d_ws, size_t ws_size,
                              hipStream_t stream) {
    const float* X = (const float*)d_in[0];
    const float* mask = (const float*)d_in[1];
    const float* W_e = (const float*)d_in[2];
    const float* b_e = (const float*)d_in[3];
    const float* gain = (const float*)d_in[4];
    const float* bias = (const float*)d_in[5];

    float* E = (float*)d_out;
    float* idxf = (float*)d_out + (size_t)NEDGE * DIMv;

    char* ws = (char*)d_ws;
    float* O9 = (float*)ws;
    int* idx_ws = (int*)(ws + (size_t)NROW * 9 * sizeof(float));
    float* dn_ws = (float*)(ws + (size_t)NROW * 9 * sizeof(float) +
                            (size_t)NEDGE * sizeof(int));

    hipLaunchKernelGGL(o_kernel, dim3((NROW + 255) / 256), dim3(256), 0, stream, X, O9);
    hipLaunchKernelGGL(topk_kernel, dim3(NROW / 4), dim3(256), 0, stream,
                       X, mask, idx_ws, dn_ws, idxf);
    hipLaunchKernelGGL(edge_kernel, dim3(NROW), dim3(256), 0, stream,
                       X, W_e, b_e, gain, bias, O9, idx_ws, dn_ws, E);
}

// Round 5
// 179.430 us; speedup vs baseline: 1.1839x; 1.1839x over previous
//
#include <hip/hip_runtime.h>
#include <stdint.h>

#define Bv 4
#define Nv 2048
#define Kv 30
#define DIMv 128
#define NROW (Bv * Nv)
#define NEDGE (Bv * Nv * Kv)

// ---------------- Kernel A: O frame precompute -> ws ----------------
__global__ __launch_bounds__(256) void o_kernel(const float* __restrict__ X,
                                                float* __restrict__ O9) {
    int id = blockIdx.x * 256 + threadIdx.x;
    if (id >= NROW) return;
    int b = id >> 11;
    int n = id & (Nv - 1);
    float o[9] = {0.f, 0.f, 0.f, 0.f, 0.f, 0.f, 0.f, 0.f, 0.f};
    if (n >= 1 && n <= Nv - 3) {
        const float* Xb = X + (size_t)b * Nv * 3;
        float lx = Xb[(Nv - 1) * 3 + 0], ly = Xb[(Nv - 1) * 3 + 1], lz = Xb[(Nv - 1) * 3 + 2];
        float ax = Xb[n * 3 + 0] - lx, ay = Xb[n * 3 + 1] - ly, az = Xb[n * 3 + 2] - lz;
        float bx = Xb[(n + 1) * 3 + 0] - lx, by = Xb[(n + 1) * 3 + 1] - ly, bz = Xb[(n + 1) * 3 + 2] - lz;
        float an = fmaxf(sqrtf(ax * ax + ay * ay + az * az), 1e-12f);
        ax /= an; ay /= an; az /= an;
        float bn = fmaxf(sqrtf(bx * bx + by * by + bz * bz), 1e-12f);
        bx /= bn; by /= bn; bz /= bn;
        float cx = ay * bz - az * by, cy = az * bx - ax * bz, cz = ax * by - ay * bx;
        float cn = fmaxf(sqrtf(cx * cx + cy * cy + cz * cz), 1e-12f);
        cx /= cn; cy /= cn; cz /= cn;
        float ox = ax - bx, oy = ay - by, oz = az - bz;
        float on = fmaxf(sqrtf(ox * ox + oy * oy + oz * oz), 1e-12f);
        ox /= on; oy /= on; oz /= on;
        float tx = oy * cz - oz * cy, ty = oz * cx - ox * cz, tz = ox * cy - oy * cx;
        o[0] = ox; o[1] = cx; o[2] = tx;
        o[3] = oy; o[4] = cy; o[5] = ty;
        o[6] = oz; o[7] = cz; o[8] = tz;
    }
#pragma unroll
    for (int i = 0; i < 9; ++i) O9[(size_t)id * 9 + i] = o[i];
}

// ---------------- Kernel B: top-K, 2 rows per wave (ILP), bit-exact ----------------
__global__ __launch_bounds__(256) void topk_kernel(const float* __restrict__ X,
                                                   const float* __restrict__ mask,
                                                   int* __restrict__ idx_ws,
                                                   float* __restrict__ dn_ws,
                                                   float* __restrict__ idxf_out) {
    const int lane = threadIdx.x & 63;
    const int wv = threadIdx.x >> 6;
    const int row0 = blockIdx.x * 8 + wv * 2;     // even; pair never straddles b
    const int b = row0 >> 11;
    const int n0 = row0 & (Nv - 1);
    const int n1 = n0 + 1;
    const float* Xb = X + (size_t)b * Nv * 3;
    const float* Mb = mask + (size_t)b * Nv;
    const float x0 = Xb[n0 * 3 + 0], y0 = Xb[n0 * 3 + 1], z0 = Xb[n0 * 3 + 2];
    const float x1 = Xb[n1 * 3 + 0], y1 = Xb[n1 * 3 + 1], z1 = Xb[n1 * 3 + 2];
    const float mi0 = Mb[n0], mi1 = Mb[n1];

    uint32_t a0[4][8], a1[4][8];
    uint32_t bmax0 = 0, bmax1 = 0;
#pragma unroll
    for (int gg = 0; gg < 4; ++gg)
#pragma unroll
        for (int s = 0; s < 8; ++s) {
            int j = (gg * 8 + s) * 64 + lane;
            float xj = Xb[j * 3 + 0], yj = Xb[j * 3 + 1], zj = Xb[j * 3 + 2];
            float mj = Mb[j];
            float dx = __fsub_rn(x0, xj), dy = __fsub_rn(y0, yj), dz = __fsub_rn(z0, zj);
            float ss = __fadd_rn(__fadd_rn(__fmul_rn(dx, dx), __fmul_rn(dy, dy)),
                                 __fmul_rn(dz, dz));
            float D = __fmul_rn(__fmul_rn(mi0, mj), __fsqrt_rn(__fadd_rn(ss, 1e-6f)));
            uint32_t bits = __float_as_uint(D);
            a0[gg][s] = bits;
            bmax0 = (bits > bmax0) ? bits : bmax0;
            dx = __fsub_rn(x1, xj); dy = __fsub_rn(y1, yj); dz = __fsub_rn(z1, zj);
            ss = __fadd_rn(__fadd_rn(__fmul_rn(dx, dx), __fmul_rn(dy, dy)),
                           __fmul_rn(dz, dz));
            D = __fmul_rn(__fmul_rn(mi1, mj), __fsqrt_rn(__fadd_rn(ss, 1e-6f)));
            bits = __float_as_uint(D);
            a1[gg][s] = bits;
            bmax1 = (bits > bmax1) ? bits : bmax1;
        }
#pragma unroll
    for (int m = 1; m < 64; m <<= 1) {
        uint32_t o0 = __shfl_xor(bmax0, m, 64);
        uint32_t o1 = __shfl_xor(bmax1, m, 64);
        bmax0 = (o0 > bmax0) ? o0 : bmax0;
        bmax1 = (o1 > bmax1) ? o1 : bmax1;
    }
    const float dmax0 = __uint_as_float(bmax0);
    const float dmax1 = __uint_as_float(bmax1);

    unsigned long long g0[4], g1[4];
#pragma unroll
    for (int gg = 0; gg < 4; ++gg) {
        unsigned long long k0 = ~0ull, k1 = ~0ull;
#pragma unroll
        for (int s = 0; s < 8; ++s) {
            int j = (gg * 8 + s) * 64 + lane;
            float mj = Mb[j];
            float adj0 = __fadd_rn(__uint_as_float(a0[gg][s]),
                                   __fmul_rn(__fsub_rn(1.f, __fmul_rn(mi0, mj)), dmax0));
            float adj1 = __fadd_rn(__uint_as_float(a1[gg][s]),
                                   __fmul_rn(__fsub_rn(1.f, __fmul_rn(mi1, mj)), dmax1));
            uint32_t b0 = __float_as_uint(adj0);
            uint32_t b1 = __float_as_uint(adj1);
            a0[gg][s] = b0;
            a1[gg][s] = b1;
            unsigned long long kk0 = ((unsigned long long)b0 << 32) | (unsigned)j;
            unsigned long long kk1 = ((unsigned long long)b1 << 32) | (unsigned)j;
            k0 = (kk0 < k0) ? kk0 : k0;
            k1 = (kk1 < k1) ? kk1 : k1;
        }
        g0[gg] = k0;
        g1[gg] = k1;
    }

    const int rk0 = row0 * Kv, rk1 = rk0 + Kv;
    for (int p = 0; p < Kv; ++p) {
        unsigned long long tA0 = (g0[0] < g0[1]) ? g0[0] : g0[1];
        unsigned long long tA1 = (g0[2] < g0[3]) ? g0[2] : g0[3];
        unsigned long long keyA = (tA0 < tA1) ? tA0 : tA1;
        unsigned long long tB0 = (g1[0] < g1[1]) ? g1[0] : g1[1];
        unsigned long long tB1 = (g1[2] < g1[3]) ? g1[2] : g1[3];
        unsigned long long keyB = (tB0 < tB1) ? tB0 : tB1;
#pragma unroll
        for (int m = 1; m < 64; m <<= 1) {
            unsigned long long oA = __shfl_xor(keyA, m, 64);
            unsigned long long oB = __shfl_xor(keyB, m, 64);
            keyA = (oA < keyA) ? oA : keyA;
            keyB = (oB < keyB) ? oB : keyB;
        }
        const uint32_t mjA = (uint32_t)(keyA & 0xFFFFFFFFull);
        const uint32_t mjB = (uint32_t)(keyB & 0xFFFFFFFFull);

        if (lane == 0) {
            idx_ws[rk0 + p] = (int)mjA;
            dn_ws[rk0 + p] = __uint_as_float((uint32_t)(keyA >> 32));
            idxf_out[rk0 + p] = (float)mjA;
            idx_ws[rk1 + p] = (int)mjB;
            dn_ws[rk1 + p] = __uint_as_float((uint32_t)(keyB >> 32));
            idxf_out[rk1 + p] = (float)mjB;
        }

#define RESCAN(ARR, GK, G, OS)                                                 \
        {                                                                      \
            unsigned long long kmin = ~0ull;                                   \
            _Pragma("unroll")                                                  \
            for (int s = 0; s < 8; ++s) {                                      \
                uint32_t val = ((uint32_t)s == (OS)) ? 0xFFFFFFFFu : ARR[G][s];\
                ARR[G][s] = val;                                               \
                unsigned long long kk = ((unsigned long long)val << 32) |      \
                    (unsigned)((((G) * 8 + s) << 6) | lane);                   \
                kmin = (kk < kmin) ? kk : kmin;                                \
            }                                                                  \
            GK[G] = kmin;                                                      \
        }
        if ((mjA & 63u) == (uint32_t)lane) {
            const uint32_t ww = mjA >> 6;
            const uint32_t og = ww >> 3;
            const uint32_t os = ww & 7u;
            if (og == 0) RESCAN(a0, g0, 0, os)
            else if (og == 1) RESCAN(a0, g0, 1, os)
            else if (og == 2) RESCAN(a0, g0, 2, os)
            else RESCAN(a0, g0, 3, os)
        }
        if ((mjB & 63u) == (uint32_t)lane) {
            const uint32_t ww = mjB >> 6;
            const uint32_t og = ww >> 3;
            const uint32_t os = ww & 7u;
            if (og == 0) RESCAN(a1, g1, 0, os)
            else if (og == 1) RESCAN(a1, g1, 1, os)
            else if (og == 2) RESCAN(a1, g1, 2, os)
            else RESCAN(a1, g1, 3, os)
        }
#undef RESCAN
    }
}

// ---------------- Kernel F: orientation features (1 thread / edge) ----------------
__device__ __forceinline__ float sgnf(float x) {
    return (x > 0.f) ? 1.f : ((x < 0.f) ? -1.f : 0.f);
}

__global__ __launch_bounds__(256) void orient_kernel(const float* __restrict__ X,
                                                     const float* __restrict__ O9,
                                                     const int* __restrict__ idx_ws,
                                                     float* __restrict__ orient) {
    const int e = blockIdx.x * 256 + threadIdx.x;   // NEDGE exact
    const int row = e / Kv;
    const int b = row >> 11;
    const int bN = b * Nv;
    const int j = idx_ws[e];

    float oi[9], oj[9];
#pragma unroll
    for (int i = 0; i < 9; ++i) {
        oi[i] = O9[(size_t)row * 9 + i];
        oj[i] = O9[((size_t)bN + j) * 9 + i];
    }
    float dx = X[((size_t)bN + j) * 3 + 0] - X[(size_t)row * 3 + 0];
    float dy = X[((size_t)bN + j) * 3 + 1] - X[(size_t)row * 3 + 1];
    float dz = X[((size_t)bN + j) * 3 + 2] - X[(size_t)row * 3 + 2];
    float u0 = oi[0] * dx + oi[1] * dy + oi[2] * dz;
    float u1 = oi[3] * dx + oi[4] * dy + oi[5] * dz;
    float u2 = oi[6] * dx + oi[7] * dy + oi[8] * dz;
    float un = fmaxf(sqrtf(u0 * u0 + u1 * u1 + u2 * u2), 1e-12f);

    float R00 = oi[0] * oj[0] + oi[3] * oj[3] + oi[6] * oj[6];
    float R11 = oi[1] * oj[1] + oi[4] * oj[4] + oi[7] * oj[7];
    float R22 = oi[2] * oj[2] + oi[5] * oj[5] + oi[8] * oj[8];
    float R21 = oi[2] * oj[1] + oi[5] * oj[4] + oi[8] * oj[7];
    float R12 = oi[1] * oj[2] + oi[4] * oj[5] + oi[7] * oj[8];
    float R02 = oi[0] * oj[2] + oi[3] * oj[5] + oi[6] * oj[8];
    float R20 = oi[2] * oj[0] + oi[5] * oj[3] + oi[8] * oj[6];
    float R10 = oi[1] * oj[0] + oi[4] * oj[3] + oi[7] * oj[6];
    float R01 = oi[0] * oj[1] + oi[3] * oj[4] + oi[6] * oj[7];
    float m0 = 0.5f * sqrtf(fabsf(1.0f + (R00 - R11 - R22)));
    float m1 = 0.5f * sqrtf(fabsf(1.0f + (-R00 + R11 - R22)));
    float m2 = 0.5f * sqrtf(fabsf(1.0f + (-R00 - R11 + R22)));
    float s0 = sgnf(R21 - R12);
    float s1 = sgnf(R02 - R20);
    float s2 = sgnf(R10 - R01);
    float tr = 1.0f + R00 + R11 + R22;
    float w4 = sqrtf(fmaxf(tr, 0.f)) * 0.5f;
    float q0 = s0 * m0, q1 = s1 * m1, q2 = s2 * m2;
    float qn = fmaxf(sqrtf(q0 * q0 + q1 * q1 + q2 * q2 + w4 * w4), 1e-12f);

    float4 lo, hi;
    lo.x = u0 / un; lo.y = u1 / un; lo.z = u2 / un; lo.w = q0 / qn;
    hi.x = q1 / qn; hi.y = q2 / qn; hi.z = w4 / qn; hi.w = 0.f;
    float* o8 = orient + (size_t)e * 8;
    *(float4*)(o8 + 0) = lo;
    *(float4*)(o8 + 4) = hi;
}

// ---------------- Kernel G: wave per row: PE/RBF + GEMM + in-reg LN ----------------
__global__ __launch_bounds__(256) void gemm_ln_kernel(const float* __restrict__ W,
                                                      const float* __restrict__ be,
                                                      const float* __restrict__ gain,
                                                      const float* __restrict__ bias,
                                                      const int* __restrict__ idx_ws,
                                                      const float* __restrict__ dn_ws,
                                                      const float* __restrict__ orient,
                                                      float* __restrict__ E) {
    __shared__ int   silds[4][32];
    __shared__ float sdn[4][32];
    __shared__ float sor[4][240];
    __shared__ float fls[4][40];

    const int lane = threadIdx.x & 63;
    const int w = threadIdx.x >> 6;
    const int row = blockIdx.x * 4 + w;
    const int n = row & (Nv - 1);
    const int rk = row * Kv;

    // per-lane constants
    const float c = -0.5756462732485115f;              // -ln(10000)/16
    const float freq = expf((float)(2 * (lane & 7)) * c);
    const float mu = (float)(lane - 16) * (20.0f / 15.0f);

    // weights: 2 adjacent channels per lane as float2
    const int c2 = 2 * lane;
    float2 wv2[40];
#pragma unroll
    for (int i = 0; i < 39; ++i) wv2[i] = *(const float2*)(W + i * DIMv + c2);
    wv2[39] = make_float2(0.f, 0.f);
    const float2 be2 = *(const float2*)(be + c2);
    const float2 g2 = *(const float2*)(gain + c2);
    const float2 b2 = *(const float2*)(bias + c2);

    // stage per-row data (coalesced; intra-wave only, no __syncthreads needed)
    if (lane < Kv) {
        silds[w][lane] = idx_ws[rk + lane];
        sdn[w][lane] = dn_ws[rk + lane];
    }
    const float* orow = orient + (size_t)rk * 8;
#pragma unroll
    for (int r = 0; r < 4; ++r) {
        int i = r * 64 + lane;
        if (i < 240) sor[w][i] = orow[i];
    }

    for (int e = 0; e < Kv; ++e) {
        const int idx = silds[w][e];    // uniform -> broadcast
        const float dn = sdn[w][e];
        float f = 0.f;
        if (lane < 16) {
            float ang = (float)(idx - n) * freq;
            f = (lane < 8) ? cosf(ang) : sinf(ang);
        } else if (lane < 32) {
            float z = (dn - mu) * 0.8f;
            f = expf(-z * z);
        } else if (lane < 39) {
            f = sor[w][e * 8 + (lane - 32)];
        }
        if (lane < 40) fls[w][lane] = f;

        float2 acc = be2;
#pragma unroll
        for (int q = 0; q < 10; ++q) {
            float4 v = *(const float4*)(&fls[w][4 * q]);
            acc.x = fmaf(v.x, wv2[4 * q + 0].x, acc.x);
            acc.y = fmaf(v.x, wv2[4 * q + 0].y, acc.y);
            acc.x = fmaf(v.y, wv2[4 * q + 1].x, acc.x);
            acc.y = fmaf(v.y, wv2[4 * q + 1].y, acc.y);
            acc.x = fmaf(v.z, wv2[4 * q + 2].x, acc.x);
            acc.y = fmaf(v.z, wv2[4 * q + 2].y, acc.y);
            acc.x = fmaf(v.w, wv2[4 * q + 3].x, acc.x);
            acc.y = fmaf(v.w, wv2[4 * q + 3].y, acc.y);
        }

        // LayerNorm over 128 channels (2 per lane, one wave)
        float s = acc.x + acc.y;
#pragma unroll
        for (int m = 1; m < 64; m <<= 1) s += __shfl_xor(s, m, 64);
        float mu_ = s * (1.0f / 128.0f);
        float d0 = acc.x - mu_, d1 = acc.y - mu_;
        float vv = d0 * d0 + d1 * d1;
#pragma unroll
        for (int m = 1; m < 64; m <<= 1) vv += __shfl_xor(vv, m, 64);
        float inv = 1.0f / (sqrtf(vv * (1.0f / 127.0f)) + 1e-6f);

        float2 r;
        r.x = g2.x * d0 * inv + b2.x;
        r.y = g2.y * d1 * inv + b2.y;
        *(float2*)(E + (size_t)(rk + e) * DIMv + c2) = r;
    }
}

// ---------------- launcher ----------------
extern "C" void kernel_launch(void* const* d_in, const int* in_sizes, int n_in,
                              void* d_out, int out_size, void* d_ws, size_t ws_size,
                              hipStream_t stream) {
    const float* X = (const float*)d_in[0];
    const float* mask = (const float*)d_in[1];
    const float* W_e = (const float*)d_in[2];
    const float* b_e = (const float*)d_in[3];
    const float* gain = (const float*)d_in[4];
    const float* bias = (const float*)d_in[5];

    float* E = (float*)d_out;
    float* idxf = (float*)d_out + (size_t)NEDGE * DIMv;

    char* ws = (char*)d_ws;
    float* O9 = (float*)ws;                                         // NROW*9 f
    int* idx_ws = (int*)(ws + (size_t)NROW * 9 * 4);                // NEDGE i32
    float* dn_ws = (float*)(ws + (size_t)NROW * 9 * 4 + (size_t)NEDGE * 4);
    float* orient = (float*)(ws + (size_t)NROW * 9 * 4 + (size_t)NEDGE * 8); // NEDGE*8 f

    hipLaunchKernelGGL(o_kernel, dim3((NROW + 255) / 256), dim3(256), 0, stream, X, O9);
    hipLaunchKernelGGL(topk_kernel, dim3(NROW / 8), dim3(256), 0, stream,
                       X, mask, idx_ws, dn_ws, idxf);
    hipLaunchKernelGGL(orient_kernel, dim3(NEDGE / 256), dim3(256), 0, stream,
                       X, O9, idx_ws, orient);
    hipLaunchKernelGGL(gemm_ln_kernel, dim3(NROW / 4), dim3(256), 0, stream,
                       W_e, b_e, gain, bias, idx_ws, dn_ws, orient, E);
}